// Round 1
// baseline (483.534 us; speedup 1.0000x reference)
//
#include <hip/hip_runtime.h>
#include <math.h>

// Problem constants (from reference setup_inputs): B=64, T=2048, D=768, fp32.
#define B_ 64
#define T_ 2048
#define D_ 768
#define D4_ (D_ / 4)      // 192 float4 per frame
#define S_ 16             // T-splits per row -> 64*16 = 1024 blocks
#define CHUNK_ (T_ / S_)  // 128 frames per chunk
#define EPS_ 1e-5f

// count[b] = clip(floor(lens*T)+1, 1, T); but when length == 1.0 exactly the
// reference uses the FULL mean over T frames (the jnp.where branch).
static __device__ __forceinline__ int row_count(float lenfrac) {
    float length = lenfrac * (float)T_;
    if (length == 1.0f) return T_;
    int c = (int)floorf(length) + 1;
    if (c < 1) c = 1;
    if (c > T_) c = T_;
    return c;
}

// ---- Kernel A: global min/max of gnoise_raw [B*D] -> ws[0]=min, ws[1]=max ----
__global__ __launch_bounds__(1024) void minmax_kernel(const float* __restrict__ g,
                                                      float* __restrict__ ws) {
    __shared__ float smin[16], smax[16];  // 1024 threads = 16 waves
    const int tid = threadIdx.x;
    float vmin = INFINITY, vmax = -INFINITY;
    const float4* g4 = (const float4*)g;
    const int n4 = B_ * D_ / 4;  // 12288
    for (int i = tid; i < n4; i += 1024) {
        float4 v = g4[i];
        vmin = fminf(vmin, fminf(fminf(v.x, v.y), fminf(v.z, v.w)));
        vmax = fmaxf(vmax, fmaxf(fmaxf(v.x, v.y), fmaxf(v.z, v.w)));
    }
    #pragma unroll
    for (int off = 32; off >= 1; off >>= 1) {
        vmin = fminf(vmin, __shfl_down(vmin, off, 64));
        vmax = fmaxf(vmax, __shfl_down(vmax, off, 64));
    }
    const int wave = tid >> 6;
    if ((tid & 63) == 0) { smin[wave] = vmin; smax[wave] = vmax; }
    __syncthreads();
    if (tid < 64) {
        // lanes 16..63 duplicate values; harmless for min/max.
        vmin = smin[tid & 15];
        vmax = smax[tid & 15];
        #pragma unroll
        for (int off = 8; off >= 1; off >>= 1) {
            vmin = fminf(vmin, __shfl_down(vmin, off, 64));
            vmax = fmaxf(vmax, __shfl_down(vmax, off, 64));
        }
        if (tid == 0) { ws[0] = vmin; ws[1] = vmax; }
    }
}

// ---- Kernel B: per-(row, chunk) partial column sums over valid frames ----
// grid (B_, S_), block 192 threads; thread t owns float4 column d4 = t.
// Writes partial[(s*B + b)*192 + t] unconditionally (ws is poisoned 0xAA).
__global__ __launch_bounds__(192) void partial_kernel(const float* __restrict__ outp,
                                                      const float* __restrict__ lens,
                                                      float* __restrict__ partial) {
    const int b = blockIdx.x;
    const int s = blockIdx.y;
    const int tid = threadIdx.x;  // 0..191
    const int tcount = row_count(lens[b]);
    const int t0 = s * CHUNK_;
    const int t1 = min(t0 + CHUNK_, tcount);

    const float4* base = (const float4*)(outp + (size_t)b * T_ * D_) + tid;
    float4 a0 = {0.f, 0.f, 0.f, 0.f}, a1 = a0, a2 = a0, a3 = a0;
    int t = t0;
    for (; t + 3 < t1; t += 4) {
        float4 v0 = base[(size_t)(t + 0) * D4_];
        float4 v1 = base[(size_t)(t + 1) * D4_];
        float4 v2 = base[(size_t)(t + 2) * D4_];
        float4 v3 = base[(size_t)(t + 3) * D4_];
        a0.x += v0.x; a0.y += v0.y; a0.z += v0.z; a0.w += v0.w;
        a1.x += v1.x; a1.y += v1.y; a1.z += v1.z; a1.w += v1.w;
        a2.x += v2.x; a2.y += v2.y; a2.z += v2.z; a2.w += v2.w;
        a3.x += v3.x; a3.y += v3.y; a3.z += v3.z; a3.w += v3.w;
    }
    for (; t < t1; ++t) {
        float4 v0 = base[(size_t)t * D4_];
        a0.x += v0.x; a0.y += v0.y; a0.z += v0.z; a0.w += v0.w;
    }
    float4 acc;
    acc.x = (a0.x + a1.x) + (a2.x + a3.x);
    acc.y = (a0.y + a1.y) + (a2.y + a3.y);
    acc.z = (a0.z + a1.z) + (a2.z + a3.z);
    acc.w = (a0.w + a1.w) + (a2.w + a3.w);

    float4* p = (float4*)partial + ((size_t)s * B_ + b) * D4_ + tid;
    *p = acc;
}

// ---- Kernel C: reduce S_ partials, divide by count, add scaled noise ----
// One thread per float4 of the [B, D] output: B*D/4 = 12288 threads.
__global__ __launch_bounds__(256) void finalize_kernel(const float* __restrict__ lens,
                                                       const float* __restrict__ graw,
                                                       const float* __restrict__ partial,
                                                       const float* __restrict__ mmws,
                                                       float* __restrict__ outp) {
    const int idx = blockIdx.x * 256 + threadIdx.x;  // float4 index over B*D/4
    if (idx >= B_ * D4_) return;
    const int b = idx / D4_;
    const int c4 = idx - b * D4_;

    const float4* part4 = (const float4*)partial;
    float4 acc = {0.f, 0.f, 0.f, 0.f};
    #pragma unroll
    for (int s = 0; s < S_; ++s) {
        float4 v = part4[((size_t)s * B_ + b) * D4_ + c4];
        acc.x += v.x; acc.y += v.y; acc.z += v.z; acc.w += v.w;
    }
    const float inv = 1.0f / (float)row_count(lens[b]);

    const float mn = mmws[0];
    const float mx = mmws[1];
    const float scale = 1.0f / (mx - mn);  // max of shifted g
    float4 g = ((const float4*)graw)[idx];
    // gnoise = EPS * ((1-9)*g + 9), g normalized to [0,1]
    float4 o;
    o.x = acc.x * inv + EPS_ * (9.0f - 8.0f * ((g.x - mn) * scale));
    o.y = acc.y * inv + EPS_ * (9.0f - 8.0f * ((g.y - mn) * scale));
    o.z = acc.z * inv + EPS_ * (9.0f - 8.0f * ((g.z - mn) * scale));
    o.w = acc.w * inv + EPS_ * (9.0f - 8.0f * ((g.w - mn) * scale));
    ((float4*)outp)[idx] = o;
}

extern "C" void kernel_launch(void* const* d_in, const int* in_sizes, int n_in,
                              void* d_out, int out_size, void* d_ws, size_t ws_size,
                              hipStream_t stream) {
    const float* outputs = (const float*)d_in[0];   // [B, T, D] fp32
    const float* lens    = (const float*)d_in[1];   // [B] fp32
    const float* graw    = (const float*)d_in[2];   // [B, D] fp32
    float* out = (float*)d_out;                     // [B, 1, D] fp32
    float* ws  = (float*)d_ws;

    // ws layout: [0..1] min/max; partials at 256 B offset: S_*B_*D_ floats (3.1 MB).
    float* partial = ws + 64;

    minmax_kernel<<<1, 1024, 0, stream>>>(graw, ws);
    partial_kernel<<<dim3(B_, S_), 192, 0, stream>>>(outputs, lens, partial);
    const int n4 = B_ * D4_;
    finalize_kernel<<<(n4 + 255) / 256, 256, 0, stream>>>(lens, graw, partial, ws, out);
}